// Round 1
// baseline (113.875 us; speedup 1.0000x reference)
//
#include <hip/hip_runtime.h>

// ES_Normalize: y[b,i,d] = a*y[b,i-1,d] + (1-a)*x[b,i,d], y[b,0,d] = x[b,0,d]
// Outputs (concatenated flat): y [B,L,D] fp32, then y[:,L-1,:] [B,D] fp32.
//
// Strategy: chunk the L axis; each thread owns one (b, chunk, d4) column strip
// of 4 consecutive floats (float4). Chunks (except chunk 0) warm up the carry
// over an H-row halo starting from y ~= x[i0-H]; since ALPHA=0.3, the initial
// carry error decays by 0.3^H = 4.3e-9 at H=16 — far below the 8.25e-2
// threshold. Chunk 0 is exact. This turns a serial scan into 131072
// independent threads (8 waves/CU) with fully coalesced float4 traffic.

constexpr int B = 64;
constexpr int L = 2048;
constexpr int D = 512;
constexpr int D4 = D / 4;       // 128 float4 columns per row
constexpr int S = 128;          // chunk length along L
constexpr int NCHUNK = L / S;   // 16
constexpr int H = 16;           // halo warm-up rows (0.3^16 ~ 4.3e-9)

__global__ __launch_bounds__(256) void es_scan_kernel(
    const float* __restrict__ x, float* __restrict__ y,
    float* __restrict__ ylast) {
  const float a = 0.3f;
  const float oma = 1.0f - a;

  const int t = blockIdx.x * blockDim.x + threadIdx.x;
  const int d4 = t % D4;
  const int rest = t / D4;
  const int chunk = rest % NCHUNK;
  const int b = rest / NCHUNK;

  const int i0 = chunk * S;
  const int start = (chunk == 0) ? 0 : (i0 - H);

  // base element offset of (b, row=0, col=d4*4)
  const size_t base = (size_t)b * L * D + (size_t)d4 * 4;

  // init carry from x[start] (exact for chunk 0, approx otherwise)
  float4 yv = *reinterpret_cast<const float4*>(x + base + (size_t)start * D);
  if (chunk == 0) {
    *reinterpret_cast<float4*>(y + base) = yv;  // y[0] = x[0]
  }

  // halo warm-up: no stores
  #pragma unroll 4
  for (int i = start + 1; i < i0; ++i) {
    const float4 xv =
        *reinterpret_cast<const float4*>(x + base + (size_t)i * D);
    yv.x = fmaf(a, yv.x, oma * xv.x);
    yv.y = fmaf(a, yv.y, oma * xv.y);
    yv.z = fmaf(a, yv.z, oma * xv.z);
    yv.w = fmaf(a, yv.w, oma * xv.w);
  }

  // main chunk: compute + store
  const int istart = (chunk == 0) ? 1 : i0;
  const int iend = i0 + S;
  #pragma unroll 4
  for (int i = istart; i < iend; ++i) {
    const float4 xv =
        *reinterpret_cast<const float4*>(x + base + (size_t)i * D);
    yv.x = fmaf(a, yv.x, oma * xv.x);
    yv.y = fmaf(a, yv.y, oma * xv.y);
    yv.z = fmaf(a, yv.z, oma * xv.z);
    yv.w = fmaf(a, yv.w, oma * xv.w);
    *reinterpret_cast<float4*>(y + base + (size_t)i * D) = yv;
  }

  // last-row output
  if (iend == L) {
    *reinterpret_cast<float4*>(ylast + (size_t)b * D + (size_t)d4 * 4) = yv;
  }
}

extern "C" void kernel_launch(void* const* d_in, const int* in_sizes, int n_in,
                              void* d_out, int out_size, void* d_ws,
                              size_t ws_size, hipStream_t stream) {
  const float* x = (const float*)d_in[0];
  float* y = (float*)d_out;
  float* ylast = y + (size_t)B * L * D;

  const int total = B * NCHUNK * D4;  // 131072
  const int block = 256;
  const int grid = total / block;     // 512
  es_scan_kernel<<<grid, block, 0, stream>>>(x, y, ylast);
}

// Round 3
// 89.645 us; speedup vs baseline: 1.2703x; 1.2703x over previous
//
#include <hip/hip_runtime.h>

// ES_Normalize: y[b,i,d] = a*y[b,i-1,d] + (1-a)*x[b,i,d], y[b,0,d] = x[b,0,d]
// Outputs (concatenated flat): y [B,L,D] fp32, then y[:,L-1,:] [B,D] fp32.
//
// Chunked-scan with decay-halo: ALPHA=0.3 decays the initial-carry error by
// 0.3^H; H=12 -> 5.3e-7, far below the 8.25e-2 threshold (chunk 0 exact).
// S=64 -> 32 chunks -> 4096 waves (4/SIMD, 16/CU) for latency hiding.
// Native ext_vector float4 (not HIP_vector_type) so nontemporal builtins
// accept it; y is write-once so nt stores skip L2 write-allocate pressure.

typedef float f32x4 __attribute__((ext_vector_type(4)));

constexpr int B = 64;
constexpr int L = 2048;
constexpr int D = 512;
constexpr int D4 = D / 4;       // 128 float4 columns per row
constexpr int S = 64;           // chunk length along L
constexpr int NCHUNK = L / S;   // 32
constexpr int H = 12;           // halo warm-up rows (0.3^12 ~ 5.3e-7)

__global__ __launch_bounds__(256) void es_scan_kernel(
    const float* __restrict__ x, float* __restrict__ y,
    float* __restrict__ ylast) {
  const float a = 0.3f;
  const float oma = 1.0f - a;

  const int t = blockIdx.x * blockDim.x + threadIdx.x;
  const int d4 = t % D4;
  const int rest = t / D4;
  const int chunk = rest % NCHUNK;
  const int b = rest / NCHUNK;

  const int i0 = chunk * S;
  const int start = (chunk == 0) ? 0 : (i0 - H);

  // base element offset of (b, row=0, col=d4*4)
  const size_t base = (size_t)b * L * D + (size_t)d4 * 4;

  // init carry from x[start] (exact for chunk 0, approx otherwise)
  f32x4 yv = *reinterpret_cast<const f32x4*>(x + base + (size_t)start * D);
  if (chunk == 0) {
    __builtin_nontemporal_store(yv, reinterpret_cast<f32x4*>(y + base));
  }

  // halo warm-up: no stores (chunk 0 skips: start==i0 there)
  #pragma unroll
  for (int k = 1; k <= H; ++k) {
    const int i = start + k;
    if (i < i0) {
      const f32x4 xv =
          *reinterpret_cast<const f32x4*>(x + base + (size_t)i * D);
      yv = a * yv + oma * xv;  // vector fma
    }
  }

  // main chunk: compute + store
  const int istart = (chunk == 0) ? 1 : i0;
  const int iend = i0 + S;
  #pragma unroll 4
  for (int i = istart; i < iend; ++i) {
    const f32x4 xv = *reinterpret_cast<const f32x4*>(x + base + (size_t)i * D);
    yv = a * yv + oma * xv;
    __builtin_nontemporal_store(
        yv, reinterpret_cast<f32x4*>(y + base + (size_t)i * D));
  }

  // last-row output
  if (iend == L) {
    __builtin_nontemporal_store(
        yv, reinterpret_cast<f32x4*>(ylast + (size_t)b * D + (size_t)d4 * 4));
  }
}

extern "C" void kernel_launch(void* const* d_in, const int* in_sizes, int n_in,
                              void* d_out, int out_size, void* d_ws,
                              size_t ws_size, hipStream_t stream) {
  const float* x = (const float*)d_in[0];
  float* y = (float*)d_out;
  float* ylast = y + (size_t)B * L * D;

  const int total = B * NCHUNK * D4;  // 262144
  const int block = 256;
  const int grid = total / block;     // 1024
  es_scan_kernel<<<grid, block, 0, stream>>>(x, y, ylast);
}